// Round 11
// baseline (128.729 us; speedup 1.0000x reference)
//
#include <hip/hip_runtime.h>
#include <hip/hip_bf16.h>
#include <stdint.h>

typedef _Float16 f16x8_t __attribute__((ext_vector_type(8)));
typedef _Float16 f16x4_t __attribute__((ext_vector_type(4)));
typedef float    f32x4_t __attribute__((ext_vector_type(4)));
typedef float    f32x16_t __attribute__((ext_vector_type(16)));

#define T_SEQ 2048
#define NH    16
#define HD    64
#define CDIM  1024
#define NTOK  4096          // B*T
#define QSCALE 0.18033688011112042f   // (1/sqrt(64)) * log2(e)
#define LOG2E  1.4426950408889634f

// ---------- async global->LDS, 16B per lane ----------
__device__ __forceinline__ void async_ld16(void* lds, const void* g) {
    __builtin_amdgcn_global_load_lds(
        (const __attribute__((address_space(1))) uint32_t*)g,
        (__attribute__((address_space(3))) uint32_t*)lds, 16, 0, 0);
}

// ---------- fused: fp32->fp16 converts (x, Wq,Wk,Wv,Wo) + mask-nonzero flag ----------
__global__ __launch_bounds__(256)
void prep_all(const float* __restrict__ x, const float* __restrict__ Wq,
              const float* __restrict__ Wk, const float* __restrict__ Wv,
              const float* __restrict__ Wo, const float* __restrict__ mask,
              _Float16* __restrict__ xh, _Float16* __restrict__ Wqkvh,
              _Float16* __restrict__ Woh, int* __restrict__ flag)
{
    const int XQ = NTOK * CDIM / 4;     // 1M float4
    const int WQ = CDIM * CDIM / 4;     // 256K float4
    int i = blockIdx.x * 256 + threadIdx.x;
    if (i < XQ + 4 * WQ) {
        const float* s; _Float16* d; int off;
        if (i < XQ) { s = x; d = xh; off = i; }
        else {
            int j = i - XQ; int w = j >> 18; off = j & (WQ - 1);
            s = (w == 0) ? Wq : (w == 1) ? Wk : (w == 2) ? Wv : Wo;
            d = (w == 3) ? Woh : Wqkvh + (size_t)w * CDIM * CDIM;
        }
        float4 v = ((const float4*)s)[off];
        f16x4_t h = {(_Float16)v.x, (_Float16)v.y, (_Float16)v.z, (_Float16)v.w};
        ((f16x4_t*)d)[off] = h;
    } else {
        int off = i - (XQ + 4 * WQ);
        float4 v = ((const float4*)mask)[off];
        if (v.x != 0.f || v.y != 0.f || v.z != 0.f || v.w != 0.f) atomicOr(flag, 1);
    }
}

// ---------- GEMM (C^T orientation): C[cc][tok] = A[cc][K] * B[tok][K]^T ----------
// MODE 0: QKV projection (A rows 3072), scatter Q [bh][t][d] (scaled) and K/V attn-chunked, fp16
// MODE 1: out projection (A rows 1024), fp32 [tok][cc] to d_out
template<int MODE>
__global__ __launch_bounds__(256)
void gemm_f16(const _Float16* __restrict__ Ag, const _Float16* __restrict__ Bg,
              const float* __restrict__ b0, const float* __restrict__ b1,
              const float* __restrict__ b2,
              _Float16* __restrict__ Qo, _Float16* __restrict__ Ko,
              _Float16* __restrict__ Vto, float* __restrict__ Fo)
{
    __shared__ _Float16 sA[2][128 * 32];
    __shared__ _Float16 sB[2][128 * 32];
    const int K = CDIM;
    const int tid  = threadIdx.x;
    const int lane = tid & 63, wv = tid >> 6;
    const int wr = wv >> 1, wc = wv & 1;
    // XCD-aware supertile swizzle (bijective; a_blk = st*8+(sb&7), b_blk = xcd*4+(sb>>3))
    const int bid = blockIdx.x;
    const int xcd = bid & 7, L = bid >> 3;        // L in [0, NWG/8)
    const int sb = L & 31, st = L >> 5;           // supertile = 8a x 4b blocks
    const int rowA0 = (st * 8 + (sb & 7)) * 128;  // cc block
    const int rowB0 = (xcd * 4 + (sb >> 3)) * 128;// token block
    const int srow = lane >> 2;
    const int scol = (lane & 3) * 8;
    const int fr = lane & 15, fg = lane >> 4;
    f32x4_t acc[4][4] = {};

#define STAGE(buf, kk) do {                                                     \
        _Pragma("unroll")                                                       \
        for (int i_ = 0; i_ < 2; ++i_) {                                        \
            const int eoff = i_ * 2048 + wv * 512;                              \
            const int r_ = i_ * 64 + wv * 16 + srow;                            \
            async_ld16(&sA[buf][eoff], Ag + (size_t)(rowA0 + r_) * K + (kk) + scol); \
            async_ld16(&sB[buf][eoff], Bg + (size_t)(rowB0 + r_) * K + (kk) + scol); \
        } } while (0)

    STAGE(0, 0);
    for (int k0 = 0; k0 < K; k0 += 32) {
        const int cur = (k0 >> 5) & 1;
        __syncthreads();                       // buf[cur] staged, prev reads done
        if (k0 + 32 < K) STAGE(cur ^ 1, k0 + 32);
        f16x8_t a[4], b[4];
#pragma unroll
        for (int mi = 0; mi < 4; ++mi)
            a[mi] = *(const f16x8_t*)&sA[cur][(wr * 64 + mi * 16 + fr) * 32 + fg * 8];
#pragma unroll
        for (int ni = 0; ni < 4; ++ni)
            b[ni] = *(const f16x8_t*)&sB[cur][(wc * 64 + ni * 16 + fr) * 32 + fg * 8];
#pragma unroll
        for (int mi = 0; mi < 4; ++mi)
#pragma unroll
            for (int ni = 0; ni < 4; ++ni)
                acc[mi][ni] = __builtin_amdgcn_mfma_f32_16x16x32_f16(a[mi], b[ni], acc[mi][ni], 0, 0, 0);
    }
#undef STAGE

    // epilogue: row = cc (4 consecutive per lane over regs), col = token (fr)
    if (MODE == 0) {
        const int which = rowA0 >> 10;                  // block-uniform: 0=Q 1=K 2=V
        const float* bp = (which == 0) ? b0 : ((which == 1) ? b1 : b2);
#pragma unroll
        for (int mi = 0; mi < 4; ++mi) {
            const int cc = (rowA0 & 1023) + wr * 64 + mi * 16 + fg * 4;  // within 1024
            const float4 bv = *(const float4*)&bp[cc];
            const int h = cc >> 6, d0 = cc & 63;
#pragma unroll
            for (int ni = 0; ni < 4; ++ni) {
                const int tok = rowB0 + wc * 64 + ni * 16 + fr;
                const int bh = (tok >> 11) * NH + h, tt = tok & (T_SEQ - 1);
                const float v0 = acc[mi][ni][0] + bv.x, v1 = acc[mi][ni][1] + bv.y;
                const float v2 = acc[mi][ni][2] + bv.z, v3 = acc[mi][ni][3] + bv.w;
                if (which == 0) {
                    f16x4_t hq = {(_Float16)(v0 * QSCALE), (_Float16)(v1 * QSCALE),
                                  (_Float16)(v2 * QSCALE), (_Float16)(v3 * QSCALE)};
                    *(f16x4_t*)&Qo[((size_t)bh * T_SEQ + tt) * HD + d0] = hq;
                } else if (which == 1) {   // K chunked: [tile][d>>3][t&63][d&7]
                    f16x4_t hk = {(_Float16)v0, (_Float16)v1, (_Float16)v2, (_Float16)v3};
                    *(f16x4_t*)&Ko[((size_t)bh * 32 + (tt >> 6)) * 4096 +
                                   (d0 >> 3) * 512 + (tt & 63) * 8 + (d0 & 7)] = hk;
                } else {                   // V chunked: [tile][(t>>3)&7][d][t&7]
                    const size_t vb_ = ((size_t)bh * 32 + (tt >> 6)) * 4096 +
                                       (size_t)((tt >> 3) & 7) * 512 + (tt & 7);
                    Vto[vb_ + (d0 + 0) * 8] = (_Float16)v0;
                    Vto[vb_ + (d0 + 1) * 8] = (_Float16)v1;
                    Vto[vb_ + (d0 + 2) * 8] = (_Float16)v2;
                    Vto[vb_ + (d0 + 3) * 8] = (_Float16)v3;
                }
            }
        }
    } else {
#pragma unroll
        for (int mi = 0; mi < 4; ++mi) {
            const int cc = rowA0 + wr * 64 + mi * 16 + fg * 4;
            const float4 bv = *(const float4*)&b0[cc];
#pragma unroll
            for (int ni = 0; ni < 4; ++ni) {
                const int tok = rowB0 + wc * 64 + ni * 16 + fr;
                float4 ov = {acc[mi][ni][0] + bv.x, acc[mi][ni][1] + bv.y,
                             acc[mi][ni][2] + bv.z, acc[mi][ni][3] + bv.w};
                *(float4*)&Fo[(size_t)tok * CDIM + cc] = ov;   // 16 full 64B lines/instr
            }
        }
    }
}

// ---------- flash attention: 32x32 MFMA, in-register P, 8 waves x 32 q-rows ----------
// grid 256 (XCD-swizzled), 512 threads; block covers 256 q-rows; KV tile = 64.
// Per-wave LDS traffic 16KB/tile (vs 20KB + P round-trip in the 16x16 form); P stays
// in registers via cvt_pkrtz + v_permlane32_swap (distinct-value operands — safe).
__global__ __launch_bounds__(512, 2)
void attn_f16(const _Float16* __restrict__ Q, const _Float16* __restrict__ Kc,
              const _Float16* __restrict__ Vc, const float* __restrict__ mask,
              const int* __restrict__ mflag, _Float16* __restrict__ AO)
{
    __shared__ __align__(16) _Float16 sK[2][4096];   // [8 dchunk][64 k][8]
    __shared__ __align__(16) _Float16 sV[2][4096];   // [8 kchunk][64 d][8]

    const int tid = threadIdx.x;
    const int lane = tid & 63, wv = tid >> 6;
    const int ln = lane & 31, hi = lane >> 5;
    const int bid = blockIdx.x;
    const int swz = (bid & 7) * 32 + (bid >> 3);     // bijective, 256 % 8 == 0
    const int qx = swz & 7, bh = swz >> 3;
    const int b = bh >> 4, h = bh & (NH - 1);
    const int q0 = qx * 256 + wv * 32;
    const _Float16* Qb  = Q  + (size_t)bh * T_SEQ * HD;
    const _Float16* Kbh = Kc + (size_t)bh * (T_SEQ * HD);
    const _Float16* Vbh = Vc + (size_t)bh * (T_SEQ * HD);
    const int soff = tid * 8;    // 512 thr x 16B = full 8KB tile per call

    // Q B-frags: B[n=q=ln][k=dc*16+hi*8+j], pre-scaled by (1/sqrt(D))*log2e
    f16x8_t qf[4];
#pragma unroll
    for (int dc = 0; dc < 4; ++dc)
        qf[dc] = *(const f16x8_t*)&Qb[(size_t)(q0 + ln) * HD + dc * 16 + hi * 8];

    f32x16_t o0 = {}, o1 = {};     // O[q-row(reg,hi)][d = gd*32 + ln]
    float m_run = -1e30f, l_run = 0.f;   // stats for q = ln (log2 domain, replicated over hi)
    const int mf = mflag[0];

    async_ld16(&sK[0][soff], Kbh + soff);
    async_ld16(&sV[0][soff], Vbh + soff);

    for (int t = 0; t < T_SEQ / 64; ++t) {
        const int cur = t & 1;
        __syncthreads();                       // buf[cur] ready (drains vmcnt)
        if (t + 1 < T_SEQ / 64) {
            const int nb = cur ^ 1, goff = (t + 1) * 4096;
            async_ld16(&sK[nb][soff], Kbh + goff + soff);
            async_ld16(&sV[nb][soff], Vbh + goff + soff);
        }

        // ---- S^T = K * Q^T (2 k-groups of 32): lane holds S[k-row][q=ln] ----
        f32x16_t s0 = {}, s1 = {};
        __builtin_amdgcn_s_setprio(1);
#pragma unroll
        for (int dc = 0; dc < 4; ++dc) {
            f16x8_t kf0 = *(const f16x8_t*)&sK[cur][(2 * dc + hi) * 512 + ln * 8];
            f16x8_t kf1 = *(const f16x8_t*)&sK[cur][(2 * dc + hi) * 512 + (32 + ln) * 8];
            s0 = __builtin_amdgcn_mfma_f32_32x32x16_f16(kf0, qf[dc], s0, 0, 0, 0);
            s1 = __builtin_amdgcn_mfma_f32_32x32x16_f16(kf1, qf[dc], s1, 0, 0, 0);
        }
        __builtin_amdgcn_s_setprio(0);

        if (mf) {
            const float* mrow = mask + (size_t)(q0 + ln) * T_SEQ + t * 64;
#pragma unroll
            for (int r2 = 0; r2 < 16; ++r2) {
                const int row = (r2 & 3) + 8 * (r2 >> 2) + 4 * hi;
                s0[r2] += mrow[row] * LOG2E;
                s1[r2] += mrow[32 + row] * LOG2E;
            }
        }

        // ---- tile max: in-lane tree (32 vals) + 1 cross-half shfl ----
        float mt[8];
#pragma unroll
        for (int i = 0; i < 8; ++i)
            mt[i] = fmaxf(fmaxf(s0[2 * i], s0[2 * i + 1]), fmaxf(s1[2 * i], s1[2 * i + 1]));
#pragma unroll
        for (int st = 4; st > 0; st >>= 1)
#pragma unroll
            for (int i = 0; i < st; ++i) mt[i] = fmaxf(mt[i], mt[i + st]);
        float tmax = fmaxf(mt[0], __shfl_xor(mt[0], 32, 64));

        if (!__all(tmax <= m_run + 8.0f)) {           // defer-max (T13)
            const float mnew = fmaxf(m_run, tmax);
            const float sc = __builtin_amdgcn_exp2f(m_run - mnew);
            m_run = mnew;
            l_run *= sc;
#pragma unroll
            for (int r2 = 0; r2 < 16; ++r2) {
                const int row = (r2 & 3) + 8 * (r2 >> 2) + 4 * hi;
                const float scr = __shfl(sc, row, 64);
                o0[r2] *= scr;
                o1[r2] *= scr;
            }
        }

        // ---- P = exp2(S - m) in place; row-sum tree ----
#pragma unroll
        for (int r2 = 0; r2 < 16; ++r2) {
            s0[r2] = __builtin_amdgcn_exp2f(s0[r2] - m_run);
            s1[r2] = __builtin_amdgcn_exp2f(s1[r2] - m_run);
        }
        float sm[8];
#pragma unroll
        for (int i = 0; i < 8; ++i)
            sm[i] = (s0[2 * i] + s0[2 * i + 1]) + (s1[2 * i] + s1[2 * i + 1]);
#pragma unroll
        for (int st = 4; st > 0; st >>= 1)
#pragma unroll
            for (int i = 0; i < st; ++i) sm[i] += sm[i + st];
        l_run += sm[0] + __shfl_xor(sm[0], 32, 64);

        // ---- P -> fp16 A-frags in-register (cvt_pkrtz + permlane32_swap) ----
        f16x8_t pa[4];
#pragma unroll
        for (int g = 0; g < 2; ++g) {
            const f32x16_t& sg = g ? s1 : s0;
            uint32_t W[8];
#pragma unroll
            for (int t2 = 0; t2 < 8; ++t2) {
                auto pk = __builtin_amdgcn_cvt_pkrtz(sg[2 * t2], sg[2 * t2 + 1]);
                W[t2] = __builtin_bit_cast(uint32_t, pk);
            }
#pragma unroll
            for (int c2 = 0; c2 < 2; ++c2) {
                uint32_t a0 = W[4 * c2 + 0], a1 = W[4 * c2 + 1];
                uint32_t a2 = W[4 * c2 + 2], a3 = W[4 * c2 + 3];
                // dst' = [dst.lo | src.lo], src' = [dst.hi | src.hi]
                asm("v_permlane32_swap_b32 %0, %1" : "+v"(a0), "+v"(a2));
                asm("v_permlane32_swap_b32 %0, %1" : "+v"(a1), "+v"(a3));
                union { uint32_t w[4]; f16x8_t v; } u;
                u.w[0] = a0; u.w[1] = a1; u.w[2] = a2; u.w[3] = a3;
                pa[g * 2 + c2] = u.v;
            }
        }

        // ---- O += P * V : A=P[q][kk], B=V^T[d][kk] ----
        __builtin_amdgcn_s_setprio(1);
#pragma unroll
        for (int c = 0; c < 4; ++c) {
            f16x8_t vb0 = *(const f16x8_t*)&sV[cur][(2 * c + hi) * 512 + ln * 8];
            f16x8_t vb1 = *(const f16x8_t*)&sV[cur][(2 * c + hi) * 512 + (32 + ln) * 8];
            o0 = __builtin_amdgcn_mfma_f32_32x32x16_f16(pa[c], vb0, o0, 0, 0, 0);
            o1 = __builtin_amdgcn_mfma_f32_32x32x16_f16(pa[c], vb1, o1, 0, 0, 0);
        }
        __builtin_amdgcn_s_setprio(0);
    }

    // ---- epilogue: normalize, write (B,T,H*D) fp16 ----
    const float linv = 1.f / l_run;
#pragma unroll
    for (int r2 = 0; r2 < 16; ++r2) {
        const int row = (r2 & 3) + 8 * (r2 >> 2) + 4 * hi;
        const float inv = __shfl(linv, row, 64);
        const size_t base = (size_t)(b * T_SEQ + q0 + row) * CDIM + h * HD;
        AO[base + ln]      = (_Float16)(o0[r2] * inv);
        AO[base + 32 + ln] = (_Float16)(o1[r2] * inv);
    }
}

extern "C" void kernel_launch(void* const* d_in, const int* in_sizes, int n_in,
                              void* d_out, int out_size, void* d_ws, size_t ws_size,
                              hipStream_t stream) {
    const float* x    = (const float*)d_in[0];
    const float* mask = (const float*)d_in[1];
    const float* Wq   = (const float*)d_in[2];
    const float* bq   = (const float*)d_in[3];
    const float* Wk   = (const float*)d_in[4];
    const float* bk   = (const float*)d_in[5];
    const float* Wv   = (const float*)d_in[6];
    const float* bv   = (const float*)d_in[7];
    const float* Wo   = (const float*)d_in[8];
    const float* bo   = (const float*)d_in[9];
    float* out = (float*)d_out;

    char* ws = (char*)d_ws;
    _Float16* xh    = (_Float16*)(ws);                    // 4096x1024  (8MB) -- reused as AO
    _Float16* Wqkvh = (_Float16*)(ws + (8u  << 20));      // 3072x1024  (6MB)
    _Float16* Woh   = (_Float16*)(ws + (14u << 20));      // 1024x1024  (2MB)
    _Float16* Qp    = (_Float16*)(ws + (16u << 20));      // (B,H,T,D)  (8MB)
    _Float16* Kc    = (_Float16*)(ws + (24u << 20));      // chunked    (8MB)
    _Float16* Vc    = (_Float16*)(ws + (32u << 20));      // chunked    (8MB)
    int* mflag      = (int*)(ws + (40u << 20));
    _Float16* AO    = xh;   // alias: x consumed by QKV GEMM before attn writes AO

    hipMemsetAsync(mflag, 0, 4, stream);
    prep_all<<<12288, 256, 0, stream>>>(x, Wq, Wk, Wv, Wo, mask, xh, Wqkvh, Woh, mflag);
    gemm_f16<0><<<768, 256, 0, stream>>>(Wqkvh, xh, bq, bk, bv, Qp, Kc, Vc, nullptr);
    attn_f16<<<256, 512, 0, stream>>>(Qp, Kc, Vc, mask, mflag, AO);
    gemm_f16<1><<<256, 256, 0, stream>>>(Woh, AO, bo, nullptr, nullptr,
                                         nullptr, nullptr, nullptr, out);
}

// Round 12
// 126.246 us; speedup vs baseline: 1.0197x; 1.0197x over previous
//
#include <hip/hip_runtime.h>
#include <hip/hip_bf16.h>
#include <stdint.h>

typedef _Float16 f16x8_t __attribute__((ext_vector_type(8)));
typedef _Float16 f16x4_t __attribute__((ext_vector_type(4)));
typedef float    f32x4_t __attribute__((ext_vector_type(4)));

#define T_SEQ 2048
#define NH    16
#define HD    64
#define CDIM  1024
#define NTOK  4096          // B*T
#define QSCALE 0.18033688011112042f   // (1/sqrt(64)) * log2(e)
#define LOG2E  1.4426950408889634f

// ---------- async global->LDS, 16B per lane ----------
__device__ __forceinline__ void async_ld16(void* lds, const void* g) {
    __builtin_amdgcn_global_load_lds(
        (const __attribute__((address_space(1))) uint32_t*)g,
        (__attribute__((address_space(3))) uint32_t*)lds, 16, 0, 0);
}

// ---------- fused: fp32->fp16 converts (x, Wq,Wk,Wv,Wo) + mask-nonzero flag ----------
__global__ __launch_bounds__(256)
void prep_all(const float* __restrict__ x, const float* __restrict__ Wq,
              const float* __restrict__ Wk, const float* __restrict__ Wv,
              const float* __restrict__ Wo, const float* __restrict__ mask,
              _Float16* __restrict__ xh, _Float16* __restrict__ Wqkvh,
              _Float16* __restrict__ Woh, int* __restrict__ flag)
{
    const int XQ = NTOK * CDIM / 4;     // 1M float4
    const int WQ = CDIM * CDIM / 4;     // 256K float4
    int i = blockIdx.x * 256 + threadIdx.x;
    if (i < XQ + 4 * WQ) {
        const float* s; _Float16* d; int off;
        if (i < XQ) { s = x; d = xh; off = i; }
        else {
            int j = i - XQ; int w = j >> 18; off = j & (WQ - 1);
            s = (w == 0) ? Wq : (w == 1) ? Wk : (w == 2) ? Wv : Wo;
            d = (w == 3) ? Woh : Wqkvh + (size_t)w * CDIM * CDIM;
        }
        float4 v = ((const float4*)s)[off];
        f16x4_t h = {(_Float16)v.x, (_Float16)v.y, (_Float16)v.z, (_Float16)v.w};
        ((f16x4_t*)d)[off] = h;
    } else {
        int off = i - (XQ + 4 * WQ);
        float4 v = ((const float4*)mask)[off];
        if (v.x != 0.f || v.y != 0.f || v.z != 0.f || v.w != 0.f) atomicOr(flag, 1);
    }
}

// ---------- GEMM (C^T orientation): C[cc][tok] = A[cc][K] * B[tok][K]^T ----------
// 3-buffer LDS + issue-early staging + counted vmcnt + raw s_barrier:
// next-tile loads stay in flight across the barrier (T3/T4 minimum; m201 safety pattern:
// each wave waits its OWN cur-tile loads via vmcnt(4) BEFORE the barrier).
// MODE 0: QKV projection, scatter Q [bh][t][d] (scaled) and K/V attn-chunked, fp16
// MODE 1: out projection, fp32 [tok][cc] to d_out
template<int MODE>
__global__ __launch_bounds__(256)
void gemm_f16(const _Float16* __restrict__ Ag, const _Float16* __restrict__ Bg,
              const float* __restrict__ b0, const float* __restrict__ b1,
              const float* __restrict__ b2,
              _Float16* __restrict__ Qo, _Float16* __restrict__ Ko,
              _Float16* __restrict__ Vto, float* __restrict__ Fo)
{
    __shared__ _Float16 sA[3][128 * 32];   // 3-buf rotation, 48KB total -> 3 blocks/CU
    __shared__ _Float16 sB[3][128 * 32];
    const int K = CDIM;
    const int tid  = threadIdx.x;
    const int lane = tid & 63, wv = tid >> 6;
    const int wr = wv >> 1, wc = wv & 1;
    // XCD-aware supertile swizzle (bijective; a_blk = st*8+(sb&7), b_blk = xcd*4+(sb>>3))
    const int bid = blockIdx.x;
    const int xcd = bid & 7, L = bid >> 3;
    const int sb = L & 31, st = L >> 5;
    const int rowA0 = (st * 8 + (sb & 7)) * 128;
    const int rowB0 = (xcd * 4 + (sb >> 3)) * 128;
    const int srow = lane >> 2;
    const int scol = (lane & 3) * 8;
    const int fr = lane & 15, fg = lane >> 4;
    f32x4_t acc[4][4] = {};

#define STAGE(buf, kk) do {                                                     \
        _Pragma("unroll")                                                       \
        for (int i_ = 0; i_ < 2; ++i_) {                                        \
            const int eoff = i_ * 2048 + wv * 512;                              \
            const int r_ = i_ * 64 + wv * 16 + srow;                            \
            async_ld16(&sA[buf][eoff], Ag + (size_t)(rowA0 + r_) * K + (kk) + scol); \
            async_ld16(&sB[buf][eoff], Bg + (size_t)(rowB0 + r_) * K + (kk) + scol); \
        } } while (0)

    STAGE(0, 0);                 // 4 loads in flight
    int cur = 0;
    for (int k0 = 0; k0 < K; k0 += 32) {
        const int nxt = (cur == 2) ? 0 : cur + 1;
        if (k0 + 32 < K) {
            STAGE(nxt, k0 + 32);                         // issue next FIRST (8 in flight)
            asm volatile("s_waitcnt vmcnt(4)" ::: "memory");  // cur landed; next stays in flight
        } else {
            asm volatile("s_waitcnt vmcnt(0)" ::: "memory");
        }
        __builtin_amdgcn_s_barrier();                    // raw barrier: NO drain
        __builtin_amdgcn_sched_barrier(0);
        f16x8_t a[4], b[4];
#pragma unroll
        for (int mi = 0; mi < 4; ++mi)
            a[mi] = *(const f16x8_t*)&sA[cur][(wr * 64 + mi * 16 + fr) * 32 + fg * 8];
#pragma unroll
        for (int ni = 0; ni < 4; ++ni)
            b[ni] = *(const f16x8_t*)&sB[cur][(wc * 64 + ni * 16 + fr) * 32 + fg * 8];
#pragma unroll
        for (int mi = 0; mi < 4; ++mi)
#pragma unroll
            for (int ni = 0; ni < 4; ++ni)
                acc[mi][ni] = __builtin_amdgcn_mfma_f32_16x16x32_f16(a[mi], b[ni], acc[mi][ni], 0, 0, 0);
        cur = nxt;
    }
#undef STAGE

    // epilogue: row = cc (4 consecutive per lane over regs), col = token (fr)
    if (MODE == 0) {
        const int which = rowA0 >> 10;                  // block-uniform: 0=Q 1=K 2=V
        const float* bp = (which == 0) ? b0 : ((which == 1) ? b1 : b2);
#pragma unroll
        for (int mi = 0; mi < 4; ++mi) {
            const int cc = (rowA0 & 1023) + wr * 64 + mi * 16 + fg * 4;  // within 1024
            const float4 bv = *(const float4*)&bp[cc];
            const int h = cc >> 6, d0 = cc & 63;
#pragma unroll
            for (int ni = 0; ni < 4; ++ni) {
                const int tok = rowB0 + wc * 64 + ni * 16 + fr;
                const int bh = (tok >> 11) * NH + h, tt = tok & (T_SEQ - 1);
                const float v0 = acc[mi][ni][0] + bv.x, v1 = acc[mi][ni][1] + bv.y;
                const float v2 = acc[mi][ni][2] + bv.z, v3 = acc[mi][ni][3] + bv.w;
                if (which == 0) {
                    f16x4_t hq = {(_Float16)(v0 * QSCALE), (_Float16)(v1 * QSCALE),
                                  (_Float16)(v2 * QSCALE), (_Float16)(v3 * QSCALE)};
                    *(f16x4_t*)&Qo[((size_t)bh * T_SEQ + tt) * HD + d0] = hq;
                } else if (which == 1) {   // K chunked: [tile][d>>3][t&63][d&7]
                    f16x4_t hk = {(_Float16)v0, (_Float16)v1, (_Float16)v2, (_Float16)v3};
                    *(f16x4_t*)&Ko[((size_t)bh * 32 + (tt >> 6)) * 4096 +
                                   (d0 >> 3) * 512 + (tt & 63) * 8 + (d0 & 7)] = hk;
                } else {                   // V chunked: [tile][(t>>3)&7][d][t&7]
                    const size_t vb_ = ((size_t)bh * 32 + (tt >> 6)) * 4096 +
                                       (size_t)((tt >> 3) & 7) * 512 + (tt & 7);
                    Vto[vb_ + (d0 + 0) * 8] = (_Float16)v0;
                    Vto[vb_ + (d0 + 1) * 8] = (_Float16)v1;
                    Vto[vb_ + (d0 + 2) * 8] = (_Float16)v2;
                    Vto[vb_ + (d0 + 3) * 8] = (_Float16)v3;
                }
            }
        }
    } else {
#pragma unroll
        for (int mi = 0; mi < 4; ++mi) {
            const int cc = rowA0 + wr * 64 + mi * 16 + fg * 4;
            const float4 bv = *(const float4*)&b0[cc];
#pragma unroll
            for (int ni = 0; ni < 4; ++ni) {
                const int tok = rowB0 + wc * 64 + ni * 16 + fr;
                float4 ov = {acc[mi][ni][0] + bv.x, acc[mi][ni][1] + bv.y,
                             acc[mi][ni][2] + bv.z, acc[mi][ni][3] + bv.w};
                *(float4*)&Fo[(size_t)tok * CDIM + cc] = ov;
            }
        }
    }
}

// ---------- flash attention (r4 structure) + 3-buf counted-vmcnt staging ----------
// 1D grid 512 (XCD-swizzled), 512 threads (8 waves); wave owns 16 q-rows; KV tile = 64
__global__ __launch_bounds__(512, 4)
void attn_f16(const _Float16* __restrict__ Q, const _Float16* __restrict__ Kc,
              const _Float16* __restrict__ Vc, const float* __restrict__ mask,
              const int* __restrict__ mflag, _Float16* __restrict__ AO)
{
    __shared__ __align__(16) _Float16 sK[3][4096];   // [8 dchunk][64 k][8], 3-buf
    __shared__ __align__(16) _Float16 sV[3][4096];   // [8 kchunk][64 d][8], 3-buf
    __shared__ __align__(16) _Float16 Ps[8][1024];   // per-wave [8 kchunk][16 q][8]

    const int tid = threadIdx.x;
    const int lane = tid & 63, wv = tid >> 6;
    const int fr = lane & 15, fg = lane >> 4;
    const int bid = blockIdx.x;
    const int swz = (bid & 7) * 64 + (bid >> 3);     // bijective, 512 % 8 == 0
    const int qx = swz & 15, bh = swz >> 4;
    const int b = bh >> 4, h = bh & (NH - 1);
    const int q0 = qx * 128 + wv * 16;
    const _Float16* Qb  = Q  + (size_t)bh * T_SEQ * HD;
    const _Float16* Kbh = Kc + (size_t)bh * (T_SEQ * HD);
    const _Float16* Vbh = Vc + (size_t)bh * (T_SEQ * HD);
    const int soff = wv * 512 + lane * 8;   // halves; lane*16B contiguous

    f16x8_t qf[2];   // Q pre-scaled by 1/sqrt(D)*log2e
#pragma unroll
    for (int dc = 0; dc < 2; ++dc)
        qf[dc] = *(const f16x8_t*)&Qb[(size_t)(q0 + fr) * HD + dc * 32 + fg * 8];

    const f16x8_t ones = {(_Float16)1.f, (_Float16)1.f, (_Float16)1.f, (_Float16)1.f,
                          (_Float16)1.f, (_Float16)1.f, (_Float16)1.f, (_Float16)1.f};
    f32x4_t o[4] = {};                 // O[q=fg*4+r][d=df*16+fr]
    f32x4_t lacc = {};                 // l[q=fg*4+r] via ones-MFMA
    float m_run = -1e30f;              // max for q = fr (log2 domain)
    const int mf = mflag[0];

    async_ld16(&sK[0][wv * 512], Kbh + soff);
    async_ld16(&sV[0][wv * 512], Vbh + soff);
    int cur = 0;

    for (int t = 0; t < T_SEQ / 64; ++t) {
        const int nxt = (cur == 2) ? 0 : cur + 1;
        if (t + 1 < T_SEQ / 64) {
            async_ld16(&sK[nxt][wv * 512], Kbh + (size_t)(t + 1) * 4096 + soff);
            async_ld16(&sV[nxt][wv * 512], Vbh + (size_t)(t + 1) * 4096 + soff);
            asm volatile("s_waitcnt vmcnt(2)" ::: "memory");  // cur landed; next in flight
        } else {
            asm volatile("s_waitcnt vmcnt(0)" ::: "memory");
        }
        __builtin_amdgcn_s_barrier();                         // raw barrier: NO drain
        __builtin_amdgcn_sched_barrier(0);

        // ---- S^T = K * Q^T : lane holds S[k=kt*16+fg*4+r][q=fr] ----
        f32x4_t s[4];
        __builtin_amdgcn_s_setprio(1);
#pragma unroll
        for (int kt = 0; kt < 4; ++kt) {
            f16x8_t kf0 = *(const f16x8_t*)&sK[cur][fg * 512       + (kt * 16 + fr) * 8];
            f16x8_t kf1 = *(const f16x8_t*)&sK[cur][(4 + fg) * 512 + (kt * 16 + fr) * 8];
            f32x4_t z = {};
            z     = __builtin_amdgcn_mfma_f32_16x16x32_f16(kf0, qf[0], z, 0, 0, 0);
            s[kt] = __builtin_amdgcn_mfma_f32_16x16x32_f16(kf1, qf[1], z, 0, 0, 0);
        }
        __builtin_amdgcn_s_setprio(0);

        // hoist V fragment reads; LDS latency hides under softmax VALU
        f16x8_t vb[2][4];
#pragma unroll
        for (int kt2 = 0; kt2 < 2; ++kt2)
#pragma unroll
            for (int df = 0; df < 4; ++df)
                vb[kt2][df] = *(const f16x8_t*)&sV[cur][(kt2 * 4 + fg) * 512 + (df * 16 + fr) * 8];

        if (mf) {
            const float* mrow = mask + (size_t)(q0 + fr) * T_SEQ + t * 64;
#pragma unroll
            for (int kt = 0; kt < 4; ++kt)
#pragma unroll
                for (int r = 0; r < 4; ++r)
                    s[kt][r] += mrow[kt * 16 + fg * 4 + r] * LOG2E;
        }

        // ---- online softmax (log2 domain; max3 tree + 2 cross-lane steps) ----
        const float t0 = fmaxf(fmaxf(s[0][0], s[0][1]), s[0][2]);
        const float t1 = fmaxf(fmaxf(s[0][3], s[1][0]), s[1][1]);
        const float t2 = fmaxf(fmaxf(s[1][2], s[1][3]), s[2][0]);
        const float t3 = fmaxf(fmaxf(s[2][1], s[2][2]), s[2][3]);
        const float t4 = fmaxf(fmaxf(s[3][0], s[3][1]), s[3][2]);
        float tmax = fmaxf(fmaxf(fmaxf(t0, t1), fmaxf(t2, t3)), fmaxf(t4, s[3][3]));
        tmax = fmaxf(tmax, __shfl_xor(tmax, 16, 64));
        tmax = fmaxf(tmax, __shfl_xor(tmax, 32, 64));

        if (!__all(tmax <= m_run + 8.0f)) {           // defer-max (T13)
            const float mnew = fmaxf(m_run, tmax);
            const float sc = __builtin_amdgcn_exp2f(m_run - mnew);
            m_run = mnew;
            float scq[4];
#pragma unroll
            for (int r = 0; r < 4; ++r)
                scq[r] = __shfl(sc, fg * 4 + r, 64);
#pragma unroll
            for (int r = 0; r < 4; ++r) {
                lacc[r] *= scq[r];
#pragma unroll
                for (int df = 0; df < 4; ++df)
                    o[df][r] *= scq[r];
            }
        }

#pragma unroll
        for (int kt = 0; kt < 4; ++kt) {
            f16x4_t hp;
#pragma unroll
            for (int r = 0; r < 4; ++r)
                hp[r] = (_Float16)__builtin_amdgcn_exp2f(s[kt][r] - m_run);
            // P[k][q=fr] -> chunk k>>3, elem k&7
            *(f16x4_t*)&Ps[wv][(kt * 2 + (fg >> 1)) * 128 + fr * 8 + (fg & 1) * 4] = hp;
        }

        asm volatile("s_waitcnt lgkmcnt(0)" ::: "memory");  // cross-lane P RAW
        __builtin_amdgcn_sched_barrier(0);

        // ---- O += P * V ; l += P * 1 ----
        __builtin_amdgcn_s_setprio(1);
#pragma unroll
        for (int kt2 = 0; kt2 < 2; ++kt2) {
            f16x8_t pa = *(const f16x8_t*)&Ps[wv][(kt2 * 4 + fg) * 128 + fr * 8];
#pragma unroll
            for (int df = 0; df < 4; ++df)
                o[df] = __builtin_amdgcn_mfma_f32_16x16x32_f16(pa, vb[kt2][df], o[df], 0, 0, 0);
            lacc = __builtin_amdgcn_mfma_f32_16x16x32_f16(pa, ones, lacc, 0, 0, 0);
        }
        __builtin_amdgcn_s_setprio(0);
        cur = nxt;
    }

    // ---- epilogue: normalize, write (B,T,H*D) fp16 ----
#pragma unroll
    for (int r = 0; r < 4; ++r) {
        const float inv = 1.f / lacc[r];
        const size_t row = (size_t)(b * T_SEQ + q0 + fg * 4 + r);
#pragma unroll
        for (int df = 0; df < 4; ++df)
            AO[row * CDIM + h * HD + df * 16 + fr] = (_Float16)(o[df][r] * inv);
    }
}

extern "C" void kernel_launch(void* const* d_in, const int* in_sizes, int n_in,
                              void* d_out, int out_size, void* d_ws, size_t ws_size,
                              hipStream_t stream) {
    const float* x    = (const float*)d_in[0];
    const float* mask = (const float*)d_in[1];
    const float* Wq   = (const float*)d_in[2];
    const float* bq   = (const float*)d_in[3];
    const float* Wk   = (const float*)d_in[4];
    const float* bk   = (const float*)d_in[5];
    const float* Wv   = (const float*)d_in[6];
    const float* bv   = (const float*)d_in[7];
    const float* Wo   = (const float*)d_in[8];
    const float* bo   = (const float*)d_in[9];
    float* out = (float*)d_out;

    char* ws = (char*)d_ws;
    _Float16* xh    = (_Float16*)(ws);                    // 4096x1024  (8MB) -- reused as AO
    _Float16* Wqkvh = (_Float16*)(ws + (8u  << 20));      // 3072x1024  (6MB)
    _Float16* Woh   = (_Float16*)(ws + (14u << 20));      // 1024x1024  (2MB)
    _Float16* Qp    = (_Float16*)(ws + (16u << 20));      // (B,H,T,D)  (8MB)
    _Float16* Kc    = (_Float16*)(ws + (24u << 20));      // chunked    (8MB)
    _Float16* Vc    = (_Float16*)(ws + (32u << 20));      // chunked    (8MB)
    int* mflag      = (int*)(ws + (40u << 20));
    _Float16* AO    = xh;   // alias: x consumed by QKV GEMM before attn writes AO

    hipMemsetAsync(mflag, 0, 4, stream);
    prep_all<<<12288, 256, 0, stream>>>(x, Wq, Wk, Wv, Wo, mask, xh, Wqkvh, Woh, mflag);
    gemm_f16<0><<<768, 256, 0, stream>>>(Wqkvh, xh, bq, bk, bv, Qp, Kc, Vc, nullptr);
    attn_f16<<<512, 512, 0, stream>>>(Qp, Kc, Vc, mask, mflag, AO);
    gemm_f16<1><<<256, 256, 0, stream>>>(Woh, AO, bo, nullptr, nullptr,
                                         nullptr, nullptr, nullptr, out);
}